// Round 5
// baseline (1525.965 us; speedup 1.0000x reference)
//
#include <hip/hip_runtime.h>
#include <math.h>

#define HH 4
#define KK 8192
#define DD 1024
#define HD 256      // d per head
#define BB 8192
#define MARGINF 10.0f

typedef __attribute__((ext_vector_type(4))) float floatx4;

// ---- software RNE float -> fp8 e4m3fn (OCP), saturate to 448 ----
__device__ __forceinline__ unsigned f2fp8(float f) {
    unsigned u  = __float_as_uint(f);
    unsigned s  = (u >> 24) & 0x80u;
    unsigned au = u & 0x7FFFFFFFu;
    float af = __uint_as_float(au);
    if (af < 0.015625f) {                               // subnormal: quantum 2^-9
        unsigned q = (unsigned)__float2int_rn(af * 512.0f);
        return s | q;
    }
    if (af > 448.0f) return s | 0x7Eu;
    unsigned lsb = (au >> 20) & 1u;
    au += 0x7FFFFu + lsb;                               // RNE into bit 20
    int e = (int)(au >> 23) - 127;
    unsigned m = (au >> 20) & 7u;
    int code = ((e + 7) << 3) | (int)m;
    if (code > 0x7E) code = 0x7E;
    return s | (unsigned)code;
}

__device__ __forceinline__ void gl_lds16(const unsigned char* g, char* l) {
    __builtin_amdgcn_global_load_lds(
        (const __attribute__((address_space(1))) unsigned int*)g,
        (__attribute__((address_space(3))) unsigned int*)l, 16, 0, 0);
}

// exact fp32 distance, identical rounding chain to the R1-R3-passing kernels
__device__ __forceinline__ float exact_dist(const float* __restrict__ Xr,
                                            const float* __restrict__ Cr,
                                            float x2, float e2) {
    float a = 0.f;
    for (int d = 0; d < 256; ++d) a = fmaf(Xr[d], Cr[d], a);
    float t1 = fmaf(-2.0f, a, x2);
    return __fadd_rn(t1, e2);
}

// ---------------- prep: exact e2 + e2p shift + fp8 codebook ----------------
__global__ __launch_bounds__(256)
void vq_prep(const float* __restrict__ C, float* __restrict__ e2w, float* __restrict__ e2p,
             unsigned char* __restrict__ Cf8) {
    int gid  = blockIdx.x * 256 + threadIdx.x;
    int code = gid >> 2;
    int part = gid & 3;
    const float4* p = (const float4*)&C[(size_t)code * HD + part * 64];
    uint4* o = (uint4*)&Cf8[(size_t)code * HD + part * 64];
    float s = 0.f;
#pragma unroll
    for (int i4 = 0; i4 < 4; ++i4) {
        unsigned w[4];
#pragma unroll
        for (int q = 0; q < 4; ++q) {
            float4 v = p[i4 * 4 + q];
            s = fmaf(v.x, v.x, s); s = fmaf(v.y, v.y, s);
            s = fmaf(v.z, v.z, s); s = fmaf(v.w, v.w, s);
            w[q] = f2fp8(v.x) | (f2fp8(v.y) << 8) | (f2fp8(v.z) << 16) | (f2fp8(v.w) << 24);
        }
        o[i4] = make_uint4(w[0], w[1], w[2], w[3]);
    }
    s += __shfl_xor(s, 1);
    s += __shfl_xor(s, 2);
    if (part == 0) { e2w[code] = s; e2p[code] = s + 1024.0f; }
}

// ---------------- main: fp8 MFMA sweep + lossless margin net + exact selection ----------------
__global__ __launch_bounds__(256, 2)
void vq_score(const float* __restrict__ X, const float* __restrict__ C,
              const unsigned char* __restrict__ Cf8,
              const float* __restrict__ e2w, const float* __restrict__ e2p,
              int* __restrict__ ctr,
              float* __restrict__ elw,
              float* __restrict__ out_q, float* __restrict__ out_codes) {
    __shared__ __align__(16) char smB[32768];   // B double-buffer; dead after sweep -> flag list
    __shared__ int   rowWave[256];
    __shared__ int   rowMinS[64];
    __shared__ float x2s[64];
    __shared__ unsigned long long rowKey[64];
    __shared__ int   cntF;
    __shared__ int   codeS[64];
    __shared__ int   claimS;

    const int tid = threadIdx.x;
    const int wid  = tid >> 6;
    const int lane = tid & 63;
    const int cl = lane & 15;
    const int qh = lane >> 4;

    // ---- claim (head, row-tile): head from HW XCC_ID so each XCD sweeps ONE 2MB fp8 codebook ----
    if (tid == 0) {
        unsigned xcc = (unsigned)__builtin_amdgcn_s_getreg(63508);  // hwreg(HW_REG_XCC_ID, 0, 32)
        int hh = (int)(xcc & 3u);
        int pos = atomicAdd(&ctr[hh], 1);
        int tries = 0;
        while (pos >= 128 && tries < 6) {   // sound: any atomicAdd return <128 is a unique claim
            hh = (hh + 1) & 3;
            pos = atomicAdd(&ctr[hh], 1);
            ++tries;
        }
        if (pos > 127) pos = 127;           // unreachable
        claimS = (hh << 8) | pos;
    }
    __syncthreads();
    const int h = claimS >> 8;
    const int rowbase = (claimS & 255) * 64;

    const unsigned char* Cf8H = Cf8 + (size_t)h * KK * HD;

    // prologue: stage chunk 0 into buffer 0 (16B granules, XOR-swizzled within each 256B row)
#pragma unroll
    for (int j = 0; j < 4; ++j) {
        int lin = j * 256 + tid;
        int code = lin >> 4, t = lin & 15;
        int g = t ^ (code & 15);
        gl_lds16(Cf8H + (size_t)code * HD + g * 16, smB + lin * 16);
    }

    // ---- x2 per row (4 lanes per row), tree identical to R1 rescore chain ----
    {
        int row = tid >> 2, part = tid & 3;
        const float4* xp = (const float4*)&X[(size_t)(rowbase + row) * DD + h * HD + part * 64];
        float s = 0.f;
#pragma unroll
        for (int i = 0; i < 16; ++i) {
            float4 v = xp[i];
            s = fmaf(v.x, v.x, s); s = fmaf(v.y, v.y, s);
            s = fmaf(v.z, v.z, s); s = fmaf(v.w, v.w, s);
        }
        s += __shfl_xor(s, 1);   // p0+p1 / p2+p3
        s += __shfl_xor(s, 2);   // (p0+p1)+(p2+p3)
        if (part == 0) x2s[row] = s;
    }

    // ---- A fragments (fp8): rows rowbase+tm*16+cl, k = kc*32 + qh*8 + j ----
    long afrag[4][8];
#pragma unroll
    for (int tm = 0; tm < 4; ++tm) {
        const float* rp = X + (size_t)(rowbase + tm * 16 + cl) * DD + h * HD + qh * 8;
#pragma unroll
        for (int kc = 0; kc < 8; ++kc) {
            float4 v0 = *(const float4*)(rp + kc * 32);
            float4 v1 = *(const float4*)(rp + kc * 32 + 4);
            unsigned lo = f2fp8(v0.x) | (f2fp8(v0.y) << 8) | (f2fp8(v0.z) << 16) | (f2fp8(v0.w) << 24);
            unsigned hi = f2fp8(v1.x) | (f2fp8(v1.y) << 8) | (f2fp8(v1.z) << 16) | (f2fp8(v1.w) << 24);
            afrag[tm][kc] = (long)(((unsigned long long)hi << 32) | lo);
        }
    }

    int best1[16], best2[16];
#pragma unroll
    for (int i = 0; i < 16; ++i) { best1[i] = 0x7FFFFFFF; best2[i] = 0x7FFFFFFF; }

    const int codeL = wid * 16 + cl;            // this lane's code column (one of 64 per chunk)
    const int q2 = qh >> 1, q1 = (qh & 1) * 8;

    for (int ch = 0; ch < 128; ++ch) {
        const int buf = ch & 1;
        __syncthreads();                        // staging of chunk ch complete
        if (ch + 1 < 128) {
#pragma unroll
            for (int j = 0; j < 4; ++j) {
                int lin = j * 256 + tid;
                int code = lin >> 4, t = lin & 15;
                int g = t ^ (code & 15);
                gl_lds16(Cf8H + (size_t)((ch + 1) * 64 + code) * HD + g * 16,
                         smB + ((buf ^ 1) << 14) + lin * 16);
            }
        }
        const float e = e2p[h * KK + ch * 64 + codeL];

        floatx4 zero = {0.f, 0.f, 0.f, 0.f};
        floatx4 acc[4];
#pragma unroll
        for (int tm = 0; tm < 4; ++tm) acc[tm] = zero;

        const char* bb = smB + (buf << 14) + codeL * 256 + q1;
#pragma unroll
        for (int kc = 0; kc < 8; ++kc) {
            long bfrag = *(const long*)(bb + (((kc * 2 + q2) ^ cl) << 4));
#pragma unroll
            for (int tm = 0; tm < 4; ++tm)
                acc[tm] = __builtin_amdgcn_mfma_f32_16x16x32_fp8_fp8(afrag[tm][kc], bfrag, acc[tm], 0, 0, 0);
        }
        // key = approx dist' (= e2+1024-2xe > 0), low 7 bits = chunk tag
#pragma unroll
        for (int tm = 0; tm < 4; ++tm)
#pragma unroll
            for (int r = 0; r < 4; ++r) {
                float dp = fmaf(-2.0f, acc[tm][r], e);
                int key = (__float_as_int(dp) & 0xFFFFFF80) | ch;
                const int sl = tm * 4 + r;
                int mx = max(key, best1[sl]);
                best1[sl] = min(best1[sl], key);
                best2[sl] = min(best2[sl], mx);
            }
    }

    // ---- per-row approx min ----
#pragma unroll
    for (int sl = 0; sl < 16; ++sl) {
        int m = best1[sl];
        m = min(m, __shfl_xor(m, 1));
        m = min(m, __shfl_xor(m, 2));
        m = min(m, __shfl_xor(m, 4));
        m = min(m, __shfl_xor(m, 8));
        if (cl == 0) {
            int row = (sl >> 2) * 16 + qh * 4 + (sl & 3);
            rowWave[wid * 64 + row] = m;
        }
    }
    __syncthreads();
    if (tid < 64) {
        rowMinS[tid] = min(min(rowWave[tid], rowWave[64 + tid]),
                           min(rowWave[128 + tid], rowWave[192 + tid]));
        rowKey[tid] = 0xFFFFFFFFFFFFFFFFull;
    }
    if (tid == 0) cntF = 0;
    __syncthreads();

    // ---- lossless candidate net ----
    // Any within-margin code is either in some slot's top-2 (rescored here) or was evicted,
    // which requires best1 AND best2 of its slot within margin -> that (row,col) is flagged
    // and its whole 128-code column is exactly rescanned below.
    int* flagL = (int*)smB;                    // dead sweep buffer; capacity 4096 >= 256*16
    {
        const float* Xr0 = X + (size_t)rowbase * DD + h * HD;
#pragma unroll
        for (int sl = 0; sl < 16; ++sl) {
            const int row = (sl >> 2) * 16 + qh * 4 + (sl & 3);
            const float lim = __int_as_float(rowMinS[row]) + MARGINF;
#pragma unroll
            for (int t = 0; t < 2; ++t) {
                int key = t ? best2[sl] : best1[sl];
                float d = __int_as_float(key & 0xFFFFFF80);   // sentinel -> NaN -> excluded
                if (d <= lim) {
                    int code = (key & 127) * 64 + codeL;
                    const float* Xr = Xr0 + (size_t)row * DD;
                    const float* Cr = C + ((size_t)h * KK + code) * HD;
                    float dd = exact_dist(Xr, Cr, x2s[row], e2w[h * KK + code]);
                    unsigned long long pk =
                        ((unsigned long long)(unsigned)__float_as_int(dd) << 32) | (unsigned)code;
                    atomicMin(&rowKey[row], pk);
                    if (t) flagL[atomicAdd(&cntF, 1)] = (row << 6) | codeL;
                }
            }
        }
    }
    __syncthreads();
    // ---- flagged-column exact rescan ----
    {
        int nF = min(cntF, 4096);
        for (int w = tid; w < nF * 128; w += 256) {
            int fi = w >> 7, t = w & 127;
            int e = flagL[fi];
            int row = e >> 6, col = e & 63;
            int code = t * 64 + col;
            const float* Xr = X + (size_t)(rowbase + row) * DD + h * HD;
            const float* Cr = C + ((size_t)h * KK + code) * HD;
            float dd = exact_dist(Xr, Cr, x2s[row], e2w[h * KK + code]);
            unsigned long long pk =
                ((unsigned long long)(unsigned)__float_as_int(dd) << 32) | (unsigned)code;
            atomicMin(&rowKey[row], pk);
        }
    }
    __syncthreads();
    if (tid < 64) {
        int w = (int)(rowKey[tid] & 0xFFFFFFFFull);
        codeS[tid] = w;
        out_codes[(size_t)(rowbase + tid) * HH + h] = (float)w;
    }
    __syncthreads();

    // ---- epilogue: quantized (STE value) + e_latent, exact as R1-R3 ----
    {
        int row = tid >> 2, part = tid & 3;
        int b = rowbase + row;
        int c = codeS[row];
        const float4* qp = (const float4*)&C[((size_t)h * KK + c) * HD + part * 64];
        const float4* xp = (const float4*)&X[(size_t)b * DD + h * HD + part * 64];
        float4*       op = (float4*)&out_q[(size_t)b * DD + h * HD + part * 64];
        float s = 0.f;
#pragma unroll
        for (int i = 0; i < 16; ++i) {
            float4 q4 = qp[i]; float4 x4 = xp[i]; float4 o;
            float d0 = __fsub_rn(q4.x, x4.x); o.x = __fadd_rn(x4.x, d0); s = fmaf(d0, d0, s);
            float d1 = __fsub_rn(q4.y, x4.y); o.y = __fadd_rn(x4.y, d1); s = fmaf(d1, d1, s);
            float d2 = __fsub_rn(q4.z, x4.z); o.z = __fadd_rn(x4.z, d2); s = fmaf(d2, d2, s);
            float d3 = __fsub_rn(q4.w, x4.w); o.w = __fadd_rn(x4.w, d3); s = fmaf(d3, d3, s);
            op[i] = o;
        }
        s += __shfl_xor(s, 1);
        s += __shfl_xor(s, 2);
        if (part == 0) elw[(size_t)b * HH + h] = s * (1.0f / 256.0f);
    }
}

// ---------------- loss: 0.25 * sum_h e_latent ----------------
__global__ __launch_bounds__(256)
void vq_loss(const float* __restrict__ elw, float* __restrict__ out_loss) {
    int b = blockIdx.x * 256 + threadIdx.x;
    if (b < BB) {
        float4 e = *(const float4*)&elw[(size_t)b * HH];
        out_loss[b] = 0.25f * (((e.x + e.y) + e.z) + e.w);
    }
}

// ================= fallback (proven R1 path, used if ws too small) =================
__global__ __launch_bounds__(256)
void vq_e2(const float* __restrict__ C, float* __restrict__ e2w) {
    int gid  = blockIdx.x * 256 + threadIdx.x;
    int code = gid >> 2;
    int part = gid & 3;
    const float4* p = (const float4*)&C[(size_t)code * HD + part * 64];
    float s = 0.f;
#pragma unroll
    for (int i = 0; i < 16; ++i) {
        float4 v = p[i];
        s = fmaf(v.x, v.x, s); s = fmaf(v.y, v.y, s);
        s = fmaf(v.z, v.z, s); s = fmaf(v.w, v.w, s);
    }
    s += __shfl_xor(s, 1);
    s += __shfl_xor(s, 2);
    if (part == 0) e2w[code] = s;
}

#define ROWS 64
#define KC   128
#define DC   32

__global__ __launch_bounds__(256, 3)
void vq_main(const float* __restrict__ X, const float* __restrict__ C,
             const float* __restrict__ e2w, float* __restrict__ elw,
             float* __restrict__ out_q, float* __restrict__ out_codes) {
    __shared__ float smem[2048 + 4096];
    float* Xs = smem;
    float* Cs = smem + 2048;
    __shared__ float x2sF[ROWS];
    __shared__ int   codeSf[ROWS];

    const int tid     = threadIdx.x;
    const int h       = blockIdx.y;
    const int rowbase = blockIdx.x * ROWS;

    {
        int row = tid >> 2, part = tid & 3;
        const float4* xp = (const float4*)&X[(size_t)(rowbase + row) * DD + h * HD + part * 64];
        float s = 0.f;
#pragma unroll
        for (int i = 0; i < 16; ++i) {
            float4 v = xp[i];
            s = fmaf(v.x, v.x, s); s = fmaf(v.y, v.y, s);
            s = fmaf(v.z, v.z, s); s = fmaf(v.w, v.w, s);
        }
        s += __shfl_xor(s, 1);
        s += __shfl_xor(s, 2);
        if (part == 0) x2sF[row] = s;
    }
    __syncthreads();

    const int rg = tid & 7;
    const int cg = tid >> 3;
    const int r0 = rg * 8;

    float x2r[8];
#pragma unroll
    for (int r = 0; r < 8; ++r) x2r[r] = x2sF[r0 + r];

    float mn[8]; int mi[8];
#pragma unroll
    for (int r = 0; r < 8; ++r) { mn[r] = 3.402823466e38f; mi[r] = 0; }

    for (int kb = 0; kb < KK; kb += KC) {
        float acc[8][4];
#pragma unroll
        for (int r = 0; r < 8; ++r)
#pragma unroll
            for (int c = 0; c < 4; ++c) acc[r][c] = 0.f;

        for (int db = 0; db < HD; db += DC) {
            __syncthreads();
#pragma unroll
            for (int rep = 0; rep < 2; ++rep) {
                int i = tid + rep * 256;
                int row = i >> 3, q = i & 7;
                float4 v = *(const float4*)&X[(size_t)(rowbase + row) * DD + h * HD + db + q * 4];
                int col = row ^ ((q & 3) << 3);
                Xs[(q * 4 + 0) * 64 + col] = v.x;
                Xs[(q * 4 + 1) * 64 + col] = v.y;
                Xs[(q * 4 + 2) * 64 + col] = v.z;
                Xs[(q * 4 + 3) * 64 + col] = v.w;
            }
#pragma unroll
            for (int rep = 0; rep < 4; ++rep) {
                int i = tid + rep * 256;
                int code = i >> 3, q = i & 7;
                float4 v = *(const float4*)&C[((size_t)(h * KK + kb + code)) * HD + db + q * 4];
                int col = code ^ ((q & 3) << 3);
                Cs[(q * 4 + 0) * 128 + col] = v.x;
                Cs[(q * 4 + 1) * 128 + col] = v.y;
                Cs[(q * 4 + 2) * 128 + col] = v.z;
                Cs[(q * 4 + 3) * 128 + col] = v.w;
            }
            __syncthreads();
#pragma unroll
            for (int t = 0; t < DC; ++t) {
                int sw = ((t >> 2) & 3) << 3;
                const float4 xa = *(const float4*)&Xs[t * 64 + (r0 ^ sw)];
                const float4 xb = *(const float4*)&Xs[t * 64 + ((r0 ^ sw) + 4)];
                const float4 cv = *(const float4*)&Cs[t * 128 + ((cg * 4) ^ sw)];
                float xv[8] = {xa.x, xa.y, xa.z, xa.w, xb.x, xb.y, xb.z, xb.w};
                float clv[4] = {cv.x, cv.y, cv.z, cv.w};
#pragma unroll
                for (int r = 0; r < 8; ++r)
#pragma unroll
                    for (int c = 0; c < 4; ++c)
                        acc[r][c] = fmaf(xv[r], clv[c], acc[r][c]);
            }
        }
        const float4 e2v = *(const float4*)&e2w[h * KK + kb + cg * 4];
        float e2a[4] = {e2v.x, e2v.y, e2v.z, e2v.w};
#pragma unroll
        for (int c = 0; c < 4; ++c) {
            int kidx = kb + cg * 4 + c;
#pragma unroll
            for (int r = 0; r < 8; ++r) {
                float t1   = x2r[r] - 2.0f * acc[r][c];
                float dist = __fadd_rn(t1, e2a[c]);
                if (dist < mn[r]) { mn[r] = dist; mi[r] = kidx; }
            }
        }
    }

    __syncthreads();
    float* redm = smem;
    int*   redi = (int*)(smem + 2048);
#pragma unroll
    for (int r = 0; r < 8; ++r) {
        redm[cg * 64 + r0 + r] = mn[r];
        redi[cg * 64 + r0 + r] = mi[r];
    }
    __syncthreads();
    if (tid < ROWS) {
        int row = tid;
        float best = redm[row]; int bi2 = redi[row];
        for (int gg = 1; gg < 32; ++gg) {
            float m = redm[gg * 64 + row]; int ii = redi[gg * 64 + row];
            if (m < best || (m == best && ii < bi2)) { best = m; bi2 = ii; }
        }
        codeSf[row] = bi2;
        out_codes[(size_t)(rowbase + row) * HH + h] = (float)bi2;
    }
    __syncthreads();

    {
        int row = tid >> 2, part = tid & 3;
        int b = rowbase + row;
        int c = codeSf[row];
        const float4* qp = (const float4*)&C[((size_t)(h * KK + c)) * HD + part * 64];
        const float4* xp = (const float4*)&X[(size_t)b * DD + h * HD + part * 64];
        float4*       op = (float4*)&out_q[(size_t)b * DD + h * HD + part * 64];
        float s = 0.f;
#pragma unroll
        for (int i = 0; i < 16; ++i) {
            float4 q4 = qp[i]; float4 x4 = xp[i]; float4 o;
            float d0 = __fsub_rn(q4.x, x4.x); o.x = __fadd_rn(x4.x, d0); s = fmaf(d0, d0, s);
            float d1 = __fsub_rn(q4.y, x4.y); o.y = __fadd_rn(x4.y, d1); s = fmaf(d1, d1, s);
            float d2 = __fsub_rn(q4.z, x4.z); o.z = __fadd_rn(x4.z, d2); s = fmaf(d2, d2, s);
            float d3 = __fsub_rn(q4.w, x4.w); o.w = __fadd_rn(x4.w, d3); s = fmaf(d3, d3, s);
            op[i] = o;
        }
        s += __shfl_xor(s, 1);
        s += __shfl_xor(s, 2);
        if (part == 0) elw[(size_t)b * HH + h] = s * (1.0f / 256.0f);
    }
}

extern "C" void kernel_launch(void* const* d_in, const int* in_sizes, int n_in,
                              void* d_out, int out_size, void* d_ws, size_t ws_size,
                              hipStream_t stream) {
    const float* X = (const float*)d_in[0];   // (B,1,D) fp32
    const float* C = (const float*)d_in[1];   // (H,K,d) fp32
    float* out      = (float*)d_out;
    float* out_loss = out;                                 // [B]
    float* out_q    = out + BB;                            // [B*D]
    float* out_code = out + BB + (size_t)BB * DD;          // [B*H] as float

    char* ws = (char*)d_ws;
    float* e2w = (float*)ws;                               // [32768]
    float* e2p = (float*)(ws + 131072);                    // [32768]
    float* elw = (float*)(ws + 262144);                    // [B*H]
    int*   ctr = (int*)(ws + 393216);                      // [4]
    unsigned char* Cf8 = (unsigned char*)(ws + 393232);    // [H*K*d] fp8

    const size_t need = 393232 + (size_t)HH * KK * HD;

    if (ws_size >= need) {
        hipMemsetAsync(ctr, 0, 16, stream);
        vq_prep<<<512, 256, 0, stream>>>(C, e2w, e2p, Cf8);
        vq_score<<<512, 256, 0, stream>>>(X, C, Cf8, e2w, e2p, ctr, elw, out_q, out_code);
        vq_loss<<<BB / 256, 256, 0, stream>>>(elw, out_loss);
    } else {
        vq_e2<<<512, 256, 0, stream>>>(C, e2w);
        dim3 grid(BB / ROWS, HH);
        vq_main<<<grid, 256, 0, stream>>>(X, C, e2w, elw, out_q, out_code);
        vq_loss<<<BB / 256, 256, 0, stream>>>(elw, out_loss);
    }
}